// Round 1
// baseline (2139.853 us; speedup 1.0000x reference)
//
#include <hip/hip_runtime.h>

// GATv2 x3 + FC on MI355X. N=50000, E=800000(+N self loops), F=128, H=4, C=32.
constexpr int FDIM = 128;   // H*C
constexpr float SLOPE = 0.2f;

// ---- float <-> ordered int (for atomicMax on floats incl. negatives) ----
__device__ __forceinline__ int float_ordered(float f) {
  int i = __float_as_int(f);
  return i >= 0 ? i : (i ^ 0x7FFFFFFF);
}
__device__ __forceinline__ float ordered_float(int i) {
  return __int_as_float(i >= 0 ? i : (i ^ 0x7FFFFFFF));
}

// ---------------- SGEMM: out = hin @ W for W in {Wl, Wr} -----------------
// hin [n,128] fp32, W [128,128] fp32 row-major. BM=64, BN=128, BK=16.
// blockIdx.y selects (Wl->xl) vs (Wr->xr).
__global__ __launch_bounds__(256) void gemm2(
    const float* __restrict__ hin, const float* __restrict__ Wl,
    const float* __restrict__ Wr, float* __restrict__ xl,
    float* __restrict__ xr, int n) {
  const float* __restrict__ W = (blockIdx.y == 0) ? Wl : Wr;
  float* __restrict__ out = (blockIdx.y == 0) ? xl : xr;
  __shared__ __align__(16) float As[64][17];
  __shared__ __align__(16) float Bs[16][132];
  const int tid = threadIdx.x;
  const int row0 = blockIdx.x * 64;
  const int tcol = (tid & 15) * 8;   // 8 output cols
  const int trow = (tid >> 4) * 4;   // 4 output rows
  float acc[4][8];
#pragma unroll
  for (int r = 0; r < 4; ++r)
#pragma unroll
    for (int c = 0; c < 8; ++c) acc[r][c] = 0.f;

  for (int k0 = 0; k0 < 128; k0 += 16) {
    // stage A: 64x16
    {
      int r = tid >> 2, c = (tid & 3) * 4;
      int gr = row0 + r;
      float4 v = make_float4(0.f, 0.f, 0.f, 0.f);
      if (gr < n) v = *(const float4*)(hin + (size_t)gr * FDIM + k0 + c);
      As[r][c + 0] = v.x; As[r][c + 1] = v.y;
      As[r][c + 2] = v.z; As[r][c + 3] = v.w;
    }
    // stage B: 16x128
    {
      int r = tid >> 5, c = (tid & 31) * 4;
      float4 v0 = *(const float4*)(W + (size_t)(k0 + r) * FDIM + c);
      float4 v1 = *(const float4*)(W + (size_t)(k0 + r + 8) * FDIM + c);
      *(float4*)&Bs[r][c] = v0;        // stride 132: 528B rows, 16B-aligned
      *(float4*)&Bs[r + 8][c] = v1;
    }
    __syncthreads();
#pragma unroll
    for (int kk = 0; kk < 16; ++kk) {
      float a0 = As[trow + 0][kk], a1 = As[trow + 1][kk];
      float a2 = As[trow + 2][kk], a3 = As[trow + 3][kk];
      float4 b0 = *(const float4*)&Bs[kk][tcol];
      float4 b1 = *(const float4*)&Bs[kk][tcol + 4];
      float bb[8] = {b0.x, b0.y, b0.z, b0.w, b1.x, b1.y, b1.z, b1.w};
#pragma unroll
      for (int c = 0; c < 8; ++c) {
        acc[0][c] = fmaf(a0, bb[c], acc[0][c]);
        acc[1][c] = fmaf(a1, bb[c], acc[1][c]);
        acc[2][c] = fmaf(a2, bb[c], acc[2][c]);
        acc[3][c] = fmaf(a3, bb[c], acc[3][c]);
      }
    }
    __syncthreads();
  }
#pragma unroll
  for (int r = 0; r < 4; ++r) {
    int gr = row0 + trow + r;
    if (gr < n) {
      float4 v0 = make_float4(acc[r][0], acc[r][1], acc[r][2], acc[r][3]);
      float4 v1 = make_float4(acc[r][4], acc[r][5], acc[r][6], acc[r][7]);
      *(float4*)(out + (size_t)gr * FDIM + tcol) = v0;
      *(float4*)(out + (size_t)gr * FDIM + tcol + 4) = v1;
    }
  }
}

// --------- pass 1: per-edge attention logits + segment max (atomicMax) ----
// wave per edge; lane i handles feature i and i+64.
__global__ __launch_bounds__(256) void attn_logits(
    const float* __restrict__ xl, const float* __restrict__ xr,
    const int* __restrict__ srcI, const int* __restrict__ dstI,
    const float* __restrict__ att, float* __restrict__ ebuf,
    int* __restrict__ mbuf, int e_cnt, int ep) {
  int wid = (int)((blockIdx.x * (size_t)blockDim.x + threadIdx.x) >> 6);
  int lane = threadIdx.x & 63;
  if (wid >= ep) return;
  int s, d;
  if (wid < e_cnt) { s = srcI[wid]; d = dstI[wid]; }
  else             { s = d = wid - e_cnt; }
  const float* xls = xl + (size_t)s * FDIM;
  const float* xrd = xr + (size_t)d * FDIM;
  float z1 = xls[lane] + xrd[lane];
  float z2 = xls[lane + 64] + xrd[lane + 64];
  float p1 = (z1 > 0.f ? z1 : SLOPE * z1) * att[lane];
  float p2 = (z2 > 0.f ? z2 : SLOPE * z2) * att[lane + 64];
#pragma unroll
  for (int off = 16; off >= 1; off >>= 1) {
    p1 += __shfl_xor(p1, off, 32);
    p2 += __shfl_xor(p2, off, 32);
  }
  if ((lane & 31) == 0) {
    int g = lane >> 5;                  // lane0 -> heads 0,2 ; lane32 -> 1,3
    ebuf[(size_t)wid * 4 + g] = p1;
    ebuf[(size_t)wid * 4 + 2 + g] = p2;
    atomicMax(mbuf + (size_t)d * 4 + g, float_ordered(p1));
    atomicMax(mbuf + (size_t)d * 4 + 2 + g, float_ordered(p2));
  }
}

// --------- pass 2: exp, denom atomicAdd, un-normalized aggregation --------
__global__ __launch_bounds__(256) void attn_agg(
    const float* __restrict__ xl, const float* __restrict__ ebuf,
    const int* __restrict__ mbuf, const int* __restrict__ srcI,
    const int* __restrict__ dstI, float* __restrict__ denom,
    float* __restrict__ accb, int e_cnt, int ep) {
  int wid = (int)((blockIdx.x * (size_t)blockDim.x + threadIdx.x) >> 6);
  int lane = threadIdx.x & 63;
  if (wid >= ep) return;
  int s, d;
  if (wid < e_cnt) { s = srcI[wid]; d = dstI[wid]; }
  else             { s = d = wid - e_cnt; }
  int g = lane >> 5;
  float m1 = ordered_float(mbuf[(size_t)d * 4 + g]);
  float m2 = ordered_float(mbuf[(size_t)d * 4 + 2 + g]);
  float a1 = expf(ebuf[(size_t)wid * 4 + g] - m1);
  float a2 = expf(ebuf[(size_t)wid * 4 + 2 + g] - m2);
  if ((lane & 31) == 0) {
    atomicAdd(denom + (size_t)d * 4 + g, a1);
    atomicAdd(denom + (size_t)d * 4 + 2 + g, a2);
  }
  const float* xls = xl + (size_t)s * FDIM;
  atomicAdd(accb + (size_t)d * FDIM + lane, a1 * xls[lane]);
  atomicAdd(accb + (size_t)d * FDIM + 64 + lane, a2 * xls[lane + 64]);
}

// --------- normalize + bias + relu -> next layer input --------------------
__global__ __launch_bounds__(256) void normalize_relu(
    const float* __restrict__ accb, const float* __restrict__ denom,
    const float* __restrict__ bias, float* __restrict__ out, int n) {
  int idx = blockIdx.x * blockDim.x + threadIdx.x;  // one float4 each
  if (idx >= n * 32) return;
  int node = idx >> 5;
  int i0 = (idx & 31) * 4;
  int h = i0 >> 5;
  float inv = 1.f / denom[(size_t)node * 4 + h];
  float4 a = *(const float4*)(accb + (size_t)node * FDIM + i0);
  float4 b = *(const float4*)(bias + i0);
  float4 r;
  r.x = fmaxf(fmaf(a.x, inv, b.x), 0.f);
  r.y = fmaxf(fmaf(a.y, inv, b.y), 0.f);
  r.z = fmaxf(fmaf(a.z, inv, b.z), 0.f);
  r.w = fmaxf(fmaf(a.w, inv, b.w), 0.f);
  *(float4*)(out + (size_t)node * FDIM + i0) = r;
}

// --------- layer-3 normalize + relu fused with final FC (128 -> 1) --------
__global__ __launch_bounds__(256) void normalize_fc(
    const float* __restrict__ accb, const float* __restrict__ denom,
    const float* __restrict__ bias, const float* __restrict__ Wf,
    const float* __restrict__ bf, float* __restrict__ out, int n) {
  int wid = (int)((blockIdx.x * (size_t)blockDim.x + threadIdx.x) >> 6);
  int lane = threadIdx.x & 63;
  if (wid >= n) return;
  int h1 = lane >> 5, h2 = 2 + (lane >> 5);
  float inv1 = 1.f / denom[(size_t)wid * 4 + h1];
  float inv2 = 1.f / denom[(size_t)wid * 4 + h2];
  float v1 = fmaxf(fmaf(accb[(size_t)wid * FDIM + lane], inv1, bias[lane]), 0.f);
  float v2 = fmaxf(fmaf(accb[(size_t)wid * FDIM + 64 + lane], inv2, bias[lane + 64]), 0.f);
  float y = v1 * Wf[lane] + v2 * Wf[lane + 64];
#pragma unroll
  for (int off = 32; off >= 1; off >>= 1) y += __shfl_xor(y, off, 64);
  if (lane == 0) out[wid] = y + bf[0];
}

extern "C" void kernel_launch(void* const* d_in, const int* in_sizes, int n_in,
                              void* d_out, int out_size, void* d_ws, size_t ws_size,
                              hipStream_t stream) {
  const float* x = (const float*)d_in[0];
  const int* ei = (const int*)d_in[1];
  const int n = in_sizes[0] / FDIM;
  const int e_cnt = in_sizes[1] / 2;
  const int ep = e_cnt + n;
  const int* srcI = ei;
  const int* dstI = ei + e_cnt;

  const float* Wl[3]  = {(const float*)d_in[2], (const float*)d_in[6], (const float*)d_in[10]};
  const float* Wr[3]  = {(const float*)d_in[3], (const float*)d_in[7], (const float*)d_in[11]};
  const float* att[3] = {(const float*)d_in[4], (const float*)d_in[8], (const float*)d_in[12]};
  const float* bs[3]  = {(const float*)d_in[5], (const float*)d_in[9], (const float*)d_in[13]};
  const float* Wf = (const float*)d_in[14];
  const float* bf = (const float*)d_in[15];

  float* ws = (float*)d_ws;
  float* xl   = ws;
  float* xr   = xl + (size_t)n * FDIM;
  float* hbuf = xr + (size_t)n * FDIM;
  float* accb = hbuf + (size_t)n * FDIM;
  float* ebuf = accb + (size_t)n * FDIM;
  int*   mbuf = (int*)(ebuf + (size_t)ep * 4);
  float* denom = (float*)(mbuf + (size_t)n * 4);

  const float* hin = x;
  const int gemmGridX = (n + 63) / 64;
  const int edgeBlocks = (ep + 3) / 4;   // 4 waves (edges) per block

  for (int L = 0; L < 3; ++L) {
    hipMemsetAsync(accb, 0, (size_t)n * FDIM * sizeof(float), stream);
    hipMemsetAsync(denom, 0, (size_t)n * 4 * sizeof(float), stream);
    hipMemsetAsync(mbuf, 0x80, (size_t)n * 4 * sizeof(int), stream);  // ~ -3.4e38
    gemm2<<<dim3(gemmGridX, 2), 256, 0, stream>>>(hin, Wl[L], Wr[L], xl, xr, n);
    attn_logits<<<edgeBlocks, 256, 0, stream>>>(xl, xr, srcI, dstI, att[L],
                                                ebuf, mbuf, e_cnt, ep);
    attn_agg<<<edgeBlocks, 256, 0, stream>>>(xl, ebuf, mbuf, srcI, dstI,
                                             denom, accb, e_cnt, ep);
    if (L < 2) {
      normalize_relu<<<(n * 32 + 255) / 256, 256, 0, stream>>>(accb, denom, bs[L], hbuf, n);
      hin = hbuf;
    } else {
      normalize_fc<<<(n + 3) / 4, 256, 0, stream>>>(accb, denom, bs[L], Wf, bf,
                                                    (float*)d_out, n);
    }
  }
}

// Round 2
// 755.518 us; speedup vs baseline: 2.8323x; 2.8323x over previous
//
#include <hip/hip_runtime.h>

// GATv2 x3 + FC on MI355X. N=50000, E=800000(+N self loops), F=128, H=4, C=32.
// R1: CSR build (counting sort by dst) + fused per-node online-softmax
// attention kernel. Eliminates all fp32 atomics and 3 passes over edges.
constexpr int FDIM = 128;   // H*C
constexpr float SLOPE = 0.2f;

// ---------------- SGEMM: out = hin @ W for W in {Wl, Wr} -----------------
__global__ __launch_bounds__(256) void gemm2(
    const float* __restrict__ hin, const float* __restrict__ Wl,
    const float* __restrict__ Wr, float* __restrict__ xl,
    float* __restrict__ xr, int n) {
  const float* __restrict__ W = (blockIdx.y == 0) ? Wl : Wr;
  float* __restrict__ out = (blockIdx.y == 0) ? xl : xr;
  __shared__ __align__(16) float As[64][17];
  __shared__ __align__(16) float Bs[16][132];
  const int tid = threadIdx.x;
  const int row0 = blockIdx.x * 64;
  const int tcol = (tid & 15) * 8;
  const int trow = (tid >> 4) * 4;
  float acc[4][8];
#pragma unroll
  for (int r = 0; r < 4; ++r)
#pragma unroll
    for (int c = 0; c < 8; ++c) acc[r][c] = 0.f;

  for (int k0 = 0; k0 < 128; k0 += 16) {
    {
      int r = tid >> 2, c = (tid & 3) * 4;
      int gr = row0 + r;
      float4 v = make_float4(0.f, 0.f, 0.f, 0.f);
      if (gr < n) v = *(const float4*)(hin + (size_t)gr * FDIM + k0 + c);
      As[r][c + 0] = v.x; As[r][c + 1] = v.y;
      As[r][c + 2] = v.z; As[r][c + 3] = v.w;
    }
    {
      int r = tid >> 5, c = (tid & 31) * 4;
      float4 v0 = *(const float4*)(W + (size_t)(k0 + r) * FDIM + c);
      float4 v1 = *(const float4*)(W + (size_t)(k0 + r + 8) * FDIM + c);
      *(float4*)&Bs[r][c] = v0;
      *(float4*)&Bs[r + 8][c] = v1;
    }
    __syncthreads();
#pragma unroll
    for (int kk = 0; kk < 16; ++kk) {
      float a0 = As[trow + 0][kk], a1 = As[trow + 1][kk];
      float a2 = As[trow + 2][kk], a3 = As[trow + 3][kk];
      float4 b0 = *(const float4*)&Bs[kk][tcol];
      float4 b1 = *(const float4*)&Bs[kk][tcol + 4];
      float bb[8] = {b0.x, b0.y, b0.z, b0.w, b1.x, b1.y, b1.z, b1.w};
#pragma unroll
      for (int c = 0; c < 8; ++c) {
        acc[0][c] = fmaf(a0, bb[c], acc[0][c]);
        acc[1][c] = fmaf(a1, bb[c], acc[1][c]);
        acc[2][c] = fmaf(a2, bb[c], acc[2][c]);
        acc[3][c] = fmaf(a3, bb[c], acc[3][c]);
      }
    }
    __syncthreads();
  }
#pragma unroll
  for (int r = 0; r < 4; ++r) {
    int gr = row0 + trow + r;
    if (gr < n) {
      float4 v0 = make_float4(acc[r][0], acc[r][1], acc[r][2], acc[r][3]);
      float4 v1 = make_float4(acc[r][4], acc[r][5], acc[r][6], acc[r][7]);
      *(float4*)(out + (size_t)gr * FDIM + tcol) = v0;
      *(float4*)(out + (size_t)gr * FDIM + tcol + 4) = v1;
    }
  }
}

// ---------------- CSR build: histogram -> scan -> scatter ----------------
__global__ __launch_bounds__(256) void hist_dst(const int* __restrict__ dstI,
                                                int* __restrict__ deg, int e_cnt) {
  int i = blockIdx.x * blockDim.x + threadIdx.x;
  int stride = gridDim.x * blockDim.x;
  for (; i < e_cnt; i += stride) atomicAdd(&deg[dstI[i]], 1);
}

__global__ __launch_bounds__(1024) void build_scan(
    const int* __restrict__ deg, int* __restrict__ rowptr,
    int* __restrict__ rowcur, int n) {
  __shared__ int lds[1024];
  const int t = threadIdx.x;
  const int chunk = (n + 1023) / 1024;
  const int b = t * chunk;
  const int e = min(b + chunk, n);
  int sum = 0;
  for (int i = b; i < e; ++i) sum += deg[i];
  lds[t] = sum;
  __syncthreads();
  for (int off = 1; off < 1024; off <<= 1) {
    int v = (t >= off) ? lds[t - off] : 0;
    __syncthreads();
    lds[t] += v;
    __syncthreads();
  }
  int run = (t == 0) ? 0 : lds[t - 1];
  for (int i = b; i < e; ++i) {
    rowptr[i] = run; rowcur[i] = run; run += deg[i];
  }
  if (t == 1023) rowptr[n] = run;
}

__global__ __launch_bounds__(256) void scatter_csr(
    const int* __restrict__ srcI, const int* __restrict__ dstI,
    int* __restrict__ rowcur, int* __restrict__ csr, int e_cnt) {
  int i = blockIdx.x * blockDim.x + threadIdx.x;
  int stride = gridDim.x * blockDim.x;
  for (; i < e_cnt; i += stride) {
    int pos = atomicAdd(&rowcur[dstI[i]], 1);
    csr[pos] = srcI[i];
  }
}

// ------- fused per-node GATv2: logits + online softmax + agg + epilogue ---
// One wave per dst node. lane handles features lane (heads 0/1) and
// lane+64 (heads 2/3). Self-loop is the initial online-softmax state.
template <int LAST>
__global__ __launch_bounds__(256) void fused_attn(
    const float* __restrict__ xl, const float* __restrict__ xr,
    const int* __restrict__ rowptr, const int* __restrict__ csr,
    const float* __restrict__ att, const float* __restrict__ bias,
    const float* __restrict__ Wf, const float* __restrict__ bf,
    float* __restrict__ out, int n) {
  const int nid = (int)((blockIdx.x * (size_t)blockDim.x + threadIdx.x) >> 6);
  const int lane = threadIdx.x & 63;
  if (nid >= n) return;
  const float attv1 = att[lane], attv2 = att[lane + 64];
  const float* xrp = xr + (size_t)nid * FDIM;
  const float xr1 = xrp[lane], xr2 = xrp[lane + 64];
  const float* xlp = xl + (size_t)nid * FDIM;
  float xa = xlp[lane], xb = xlp[lane + 64];

  // self edge -> initial state
  float z1 = xa + xr1, z2 = xb + xr2;
  float p1 = (z1 > 0.f ? z1 : SLOPE * z1) * attv1;
  float p2 = (z2 > 0.f ? z2 : SLOPE * z2) * attv2;
#pragma unroll
  for (int off = 16; off >= 1; off >>= 1) {
    p1 += __shfl_xor(p1, off, 32);
    p2 += __shfl_xor(p2, off, 32);
  }
  float m1 = p1, m2 = p2;
  float s1 = 1.f, s2 = 1.f;
  float acc1 = xa, acc2 = xb;

  const int rs = rowptr[nid], re = rowptr[nid + 1];
  float xaN = 0.f, xbN = 0.f;
  if (rs < re) {
    int s0 = csr[rs];
    xaN = xl[(size_t)s0 * FDIM + lane];
    xbN = xl[(size_t)s0 * FDIM + 64 + lane];
  }
  for (int j = rs; j < re; ++j) {
    xa = xaN; xb = xbN;
    if (j + 1 < re) {  // prefetch next src row
      int sn = csr[j + 1];
      xaN = xl[(size_t)sn * FDIM + lane];
      xbN = xl[(size_t)sn * FDIM + 64 + lane];
    }
    z1 = xa + xr1; z2 = xb + xr2;
    p1 = (z1 > 0.f ? z1 : SLOPE * z1) * attv1;
    p2 = (z2 > 0.f ? z2 : SLOPE * z2) * attv2;
#pragma unroll
    for (int off = 16; off >= 1; off >>= 1) {
      p1 += __shfl_xor(p1, off, 32);
      p2 += __shfl_xor(p2, off, 32);
    }
    float mn1 = fmaxf(m1, p1), mn2 = fmaxf(m2, p2);
    float sc1 = __expf(m1 - mn1), sc2 = __expf(m2 - mn2);
    float w1 = __expf(p1 - mn1), w2 = __expf(p2 - mn2);
    s1 = fmaf(s1, sc1, w1);
    s2 = fmaf(s2, sc2, w2);
    acc1 = fmaf(acc1, sc1, w1 * xa);
    acc2 = fmaf(acc2, sc2, w2 * xb);
    m1 = mn1; m2 = mn2;
  }
  const float v1 = acc1 / s1 + bias[lane];
  const float v2 = acc2 / s2 + bias[lane + 64];
  if (LAST == 0) {
    out[(size_t)nid * FDIM + lane] = fmaxf(v1, 0.f);
    out[(size_t)nid * FDIM + 64 + lane] = fmaxf(v2, 0.f);
  } else {
    float y = fmaxf(v1, 0.f) * Wf[lane] + fmaxf(v2, 0.f) * Wf[lane + 64];
#pragma unroll
    for (int off = 32; off >= 1; off >>= 1) y += __shfl_xor(y, off, 64);
    if (lane == 0) out[nid] = y + bf[0];
  }
}

extern "C" void kernel_launch(void* const* d_in, const int* in_sizes, int n_in,
                              void* d_out, int out_size, void* d_ws, size_t ws_size,
                              hipStream_t stream) {
  const float* x = (const float*)d_in[0];
  const int* ei = (const int*)d_in[1];
  const int n = in_sizes[0] / FDIM;
  const int e_cnt = in_sizes[1] / 2;
  const int* srcI = ei;
  const int* dstI = ei + e_cnt;

  const float* Wl[3]  = {(const float*)d_in[2], (const float*)d_in[6], (const float*)d_in[10]};
  const float* Wr[3]  = {(const float*)d_in[3], (const float*)d_in[7], (const float*)d_in[11]};
  const float* att[3] = {(const float*)d_in[4], (const float*)d_in[8], (const float*)d_in[12]};
  const float* bs[3]  = {(const float*)d_in[5], (const float*)d_in[9], (const float*)d_in[13]};
  const float* Wf = (const float*)d_in[14];
  const float* bf = (const float*)d_in[15];

  float* ws = (float*)d_ws;
  float* xl   = ws;
  float* xr   = xl + (size_t)n * FDIM;
  float* hbuf = xr + (size_t)n * FDIM;
  int* deg    = (int*)(hbuf + (size_t)n * FDIM);
  int* rowptr = deg + n;
  int* rowcur = rowptr + n + 1;
  int* csr    = rowcur + n;

  // ---- CSR build (once per call; serves all 3 layers) ----
  hipMemsetAsync(deg, 0, (size_t)n * sizeof(int), stream);
  hist_dst<<<(e_cnt + 255) / 256, 256, 0, stream>>>(dstI, deg, e_cnt);
  build_scan<<<1, 1024, 0, stream>>>(deg, rowptr, rowcur, n);
  scatter_csr<<<(e_cnt + 255) / 256, 256, 0, stream>>>(srcI, dstI, rowcur, csr, e_cnt);

  const float* hin = x;
  const int gemmGridX = (n + 63) / 64;
  const int nodeBlocks = (n + 3) / 4;  // 4 waves (nodes) per block

  for (int L = 0; L < 3; ++L) {
    gemm2<<<dim3(gemmGridX, 2), 256, 0, stream>>>(hin, Wl[L], Wr[L], xl, xr, n);
    if (L < 2) {
      fused_attn<0><<<nodeBlocks, 256, 0, stream>>>(xl, xr, rowptr, csr, att[L],
                                                    bs[L], nullptr, nullptr, hbuf, n);
      hin = hbuf;
    } else {
      fused_attn<1><<<nodeBlocks, 256, 0, stream>>>(xl, xr, rowptr, csr, att[L],
                                                    bs[L], Wf, bf, (float*)d_out, n);
    }
  }
}

// Round 3
// 665.454 us; speedup vs baseline: 3.2156x; 1.1353x over previous
//
#include <hip/hip_runtime.h>

// GATv2 x3 + FC on MI355X. N=50000, E=800000(+N self loops), F=128, H=4, C=32.
// R2: (a) fused_attn processes 2 edges/wave (per-half online softmax, merged
//     at end), float4 gathers, 8-lane head reductions -> ~3x less VALU/edge.
//     (b) gemm2 with 8x8 register tile, k-major A tile -> ~94% FMA density.
constexpr int FDIM = 128;   // H*C
constexpr float SLOPE = 0.2f;

__device__ __forceinline__ float lrelu(float x) {
  return x > 0.f ? x : x * SLOPE;
}

// ---------------- SGEMM: out = hin @ W for W in {Wl, Wr} -----------------
// BM=128, BN=128, BK=16, 256 threads, 8x8 per-thread register tile.
__global__ __launch_bounds__(256) void gemm2(
    const float* __restrict__ hin, const float* __restrict__ Wl,
    const float* __restrict__ Wr, float* __restrict__ xl,
    float* __restrict__ xr, int n) {
  const float* __restrict__ W = (blockIdx.y == 0) ? Wl : Wr;
  float* __restrict__ out = (blockIdx.y == 0) ? xl : xr;
  __shared__ __align__(16) float At[16][132];  // k-major A: At[k][row]
  __shared__ __align__(16) float Bs[16][132];
  const int tid = threadIdx.x;
  const int row0 = blockIdx.x * 128;
  const int tr = (tid >> 4) * 8;
  const int tc = (tid & 15) * 8;
  float acc[8][8];
#pragma unroll
  for (int i = 0; i < 8; ++i)
#pragma unroll
    for (int j = 0; j < 8; ++j) acc[i][j] = 0.f;

  for (int k0 = 0; k0 < 128; k0 += 16) {
    {  // stage A (transposed): rows r=tid>>1, cols c=(tid&1)*8
      int r = tid >> 1, c = (tid & 1) * 8;
      int gr = row0 + r;
      float4 v0 = make_float4(0.f, 0.f, 0.f, 0.f), v1 = v0;
      if (gr < n) {
        v0 = *(const float4*)(hin + (size_t)gr * FDIM + k0 + c);
        v1 = *(const float4*)(hin + (size_t)gr * FDIM + k0 + c + 4);
      }
      At[c + 0][r] = v0.x; At[c + 1][r] = v0.y;
      At[c + 2][r] = v0.z; At[c + 3][r] = v0.w;
      At[c + 4][r] = v1.x; At[c + 5][r] = v1.y;
      At[c + 6][r] = v1.z; At[c + 7][r] = v1.w;
    }
    {  // stage B: row r=tid>>4, cols (tid&15)*8
      int r = tid >> 4, c = (tid & 15) * 8;
      float4 v0 = *(const float4*)(W + (size_t)(k0 + r) * FDIM + c);
      float4 v1 = *(const float4*)(W + (size_t)(k0 + r) * FDIM + c + 4);
      *(float4*)&Bs[r][c] = v0;
      *(float4*)&Bs[r][c + 4] = v1;
    }
    __syncthreads();
#pragma unroll
    for (int kk = 0; kk < 16; ++kk) {
      float4 a0 = *(const float4*)&At[kk][tr];
      float4 a1 = *(const float4*)&At[kk][tr + 4];
      float4 b0 = *(const float4*)&Bs[kk][tc];
      float4 b1 = *(const float4*)&Bs[kk][tc + 4];
      float av[8] = {a0.x, a0.y, a0.z, a0.w, a1.x, a1.y, a1.z, a1.w};
      float bv[8] = {b0.x, b0.y, b0.z, b0.w, b1.x, b1.y, b1.z, b1.w};
#pragma unroll
      for (int i = 0; i < 8; ++i)
#pragma unroll
        for (int j = 0; j < 8; ++j)
          acc[i][j] = fmaf(av[i], bv[j], acc[i][j]);
    }
    __syncthreads();
  }
#pragma unroll
  for (int i = 0; i < 8; ++i) {
    int gr = row0 + tr + i;
    if (gr < n) {
      float4 o0 = make_float4(acc[i][0], acc[i][1], acc[i][2], acc[i][3]);
      float4 o1 = make_float4(acc[i][4], acc[i][5], acc[i][6], acc[i][7]);
      *(float4*)(out + (size_t)gr * FDIM + tc) = o0;
      *(float4*)(out + (size_t)gr * FDIM + tc + 4) = o1;
    }
  }
}

// ---------------- CSR build: histogram -> scan -> scatter ----------------
__global__ __launch_bounds__(256) void hist_dst(const int* __restrict__ dstI,
                                                int* __restrict__ deg, int e_cnt) {
  int i = blockIdx.x * blockDim.x + threadIdx.x;
  int stride = gridDim.x * blockDim.x;
  for (; i < e_cnt; i += stride) atomicAdd(&deg[dstI[i]], 1);
}

__global__ __launch_bounds__(1024) void build_scan(
    const int* __restrict__ deg, int* __restrict__ rowptr,
    int* __restrict__ rowcur, int n) {
  __shared__ int lds[1024];
  const int t = threadIdx.x;
  const int chunk = (n + 1023) / 1024;
  const int b = t * chunk;
  const int e = min(b + chunk, n);
  int sum = 0;
  for (int i = b; i < e; ++i) sum += deg[i];
  lds[t] = sum;
  __syncthreads();
  for (int off = 1; off < 1024; off <<= 1) {
    int v = (t >= off) ? lds[t - off] : 0;
    __syncthreads();
    lds[t] += v;
    __syncthreads();
  }
  int run = (t == 0) ? 0 : lds[t - 1];
  for (int i = b; i < e; ++i) {
    rowptr[i] = run; rowcur[i] = run; run += deg[i];
  }
  if (t == 1023) rowptr[n] = run;
}

__global__ __launch_bounds__(256) void scatter_csr(
    const int* __restrict__ srcI, const int* __restrict__ dstI,
    int* __restrict__ rowcur, int* __restrict__ csr, int e_cnt) {
  int i = blockIdx.x * blockDim.x + threadIdx.x;
  int stride = gridDim.x * blockDim.x;
  for (; i < e_cnt; i += stride) {
    int pos = atomicAdd(&rowcur[dstI[i]], 1);
    csr[pos] = srcI[i];
  }
}

// ------- fused per-node GATv2: 2 edges per wave, online softmax ----------
// lane = h2*32 + q. Half h2 processes edges rs+2t+h2. Lane q covers
// features q*4..q*4+3 (head q>>3). Self-loop seeds half 0's state.
template <int LAST>
__global__ __launch_bounds__(256) void fused_attn(
    const float* __restrict__ xl, const float* __restrict__ xr,
    const int* __restrict__ rowptr, const int* __restrict__ csr,
    const float* __restrict__ att, const float* __restrict__ bias,
    const float* __restrict__ Wf, const float* __restrict__ bf,
    float* __restrict__ out, int n) {
  const int nid = (int)((blockIdx.x * (size_t)blockDim.x + threadIdx.x) >> 6);
  const int lane = threadIdx.x & 63;
  if (nid >= n) return;
  const int h2 = lane >> 5;
  const int q = lane & 31;
  const int f4 = q * 4;
  const float4 att4 = *(const float4*)(att + f4);
  const float4 xr4 = *(const float4*)(xr + (size_t)nid * FDIM + f4);
  const float4 xld4 = *(const float4*)(xl + (size_t)nid * FDIM + f4);

  // self-edge logit
  float ps = fmaf(lrelu(xld4.x + xr4.x), att4.x,
             fmaf(lrelu(xld4.y + xr4.y), att4.y,
             fmaf(lrelu(xld4.z + xr4.z), att4.z,
                  lrelu(xld4.w + xr4.w) * att4.w)));
  ps += __shfl_xor(ps, 1);
  ps += __shfl_xor(ps, 2);
  ps += __shfl_xor(ps, 4);

  float m = (h2 == 0) ? ps : -1e30f;
  float s = (h2 == 0) ? 1.f : 0.f;
  float4 acc = (h2 == 0) ? xld4 : make_float4(0.f, 0.f, 0.f, 0.f);

  const int rs = rowptr[nid], re = rowptr[nid + 1];
  int jj = rs + h2;
  bool v = jj < re;
  int sidx = v ? csr[jj] : 0;
  float4 xa4 = make_float4(0.f, 0.f, 0.f, 0.f);
  if (v) xa4 = *(const float4*)(xl + (size_t)sidx * FDIM + f4);

  for (int t = rs; t < re; t += 2) {
    // prefetch next pair
    int jn = t + 2 + h2;
    bool vn = jn < re;
    int sn = vn ? csr[jn] : 0;
    float4 xn = make_float4(0.f, 0.f, 0.f, 0.f);
    if (vn) xn = *(const float4*)(xl + (size_t)sn * FDIM + f4);
    // logit for this half's edge
    float p = fmaf(lrelu(xa4.x + xr4.x), att4.x,
              fmaf(lrelu(xa4.y + xr4.y), att4.y,
              fmaf(lrelu(xa4.z + xr4.z), att4.z,
                   lrelu(xa4.w + xr4.w) * att4.w)));
    p += __shfl_xor(p, 1);
    p += __shfl_xor(p, 2);
    p += __shfl_xor(p, 4);
    if (v) {
      float mn = fmaxf(m, p);
      float sc = __expf(m - mn);
      float w = __expf(p - mn);
      s = fmaf(s, sc, w);
      acc.x = fmaf(acc.x, sc, w * xa4.x);
      acc.y = fmaf(acc.y, sc, w * xa4.y);
      acc.z = fmaf(acc.z, sc, w * xa4.z);
      acc.w = fmaf(acc.w, sc, w * xa4.w);
      m = mn;
    }
    v = vn; xa4 = xn;
  }

  // merge the two halves' online-softmax states
  float mo = __shfl_xor(m, 32);
  float so = __shfl_xor(s, 32);
  float4 ao;
  ao.x = __shfl_xor(acc.x, 32);
  ao.y = __shfl_xor(acc.y, 32);
  ao.z = __shfl_xor(acc.z, 32);
  ao.w = __shfl_xor(acc.w, 32);
  float M = fmaxf(m, mo);
  float e0 = __expf(m - M), e1 = __expf(mo - M);
  float S = fmaf(s, e0, so * e1);
  float inv = 1.f / S;
  const float4 b4 = *(const float4*)(bias + f4);
  float v0 = fmaxf(fmaf(fmaf(acc.x, e0, ao.x * e1), inv, b4.x), 0.f);
  float v1 = fmaxf(fmaf(fmaf(acc.y, e0, ao.y * e1), inv, b4.y), 0.f);
  float v2 = fmaxf(fmaf(fmaf(acc.z, e0, ao.z * e1), inv, b4.z), 0.f);
  float v3 = fmaxf(fmaf(fmaf(acc.w, e0, ao.w * e1), inv, b4.w), 0.f);

  if (LAST == 0) {
    if (h2 == 0)
      *(float4*)(out + (size_t)nid * FDIM + f4) = make_float4(v0, v1, v2, v3);
  } else {
    const float4 wf4 = *(const float4*)(Wf + f4);
    float y = fmaf(v0, wf4.x, fmaf(v1, wf4.y, fmaf(v2, wf4.z, v3 * wf4.w)));
    if (h2) y = 0.f;  // both halves hold merged copy; count once
#pragma unroll
    for (int off = 32; off >= 1; off >>= 1) y += __shfl_xor(y, off, 64);
    if (lane == 0) out[nid] = y + bf[0];
  }
}

extern "C" void kernel_launch(void* const* d_in, const int* in_sizes, int n_in,
                              void* d_out, int out_size, void* d_ws, size_t ws_size,
                              hipStream_t stream) {
  const float* x = (const float*)d_in[0];
  const int* ei = (const int*)d_in[1];
  const int n = in_sizes[0] / FDIM;
  const int e_cnt = in_sizes[1] / 2;
  const int* srcI = ei;
  const int* dstI = ei + e_cnt;

  const float* Wl[3]  = {(const float*)d_in[2], (const float*)d_in[6], (const float*)d_in[10]};
  const float* Wr[3]  = {(const float*)d_in[3], (const float*)d_in[7], (const float*)d_in[11]};
  const float* att[3] = {(const float*)d_in[4], (const float*)d_in[8], (const float*)d_in[12]};
  const float* bs[3]  = {(const float*)d_in[5], (const float*)d_in[9], (const float*)d_in[13]};
  const float* Wf = (const float*)d_in[14];
  const float* bf = (const float*)d_in[15];

  float* ws = (float*)d_ws;
  float* xl   = ws;
  float* xr   = xl + (size_t)n * FDIM;
  float* hbuf = xr + (size_t)n * FDIM;
  int* deg    = (int*)(hbuf + (size_t)n * FDIM);
  int* rowptr = deg + n;
  int* rowcur = rowptr + n + 1;
  int* csr    = rowcur + n;

  // ---- CSR build (once per call; serves all 3 layers) ----
  hipMemsetAsync(deg, 0, (size_t)n * sizeof(int), stream);
  hist_dst<<<(e_cnt + 255) / 256, 256, 0, stream>>>(dstI, deg, e_cnt);
  build_scan<<<1, 1024, 0, stream>>>(deg, rowptr, rowcur, n);
  scatter_csr<<<(e_cnt + 255) / 256, 256, 0, stream>>>(srcI, dstI, rowcur, csr, e_cnt);

  const float* hin = x;
  const int gemmGridX = (n + 127) / 128;
  const int nodeBlocks = (n + 3) / 4;  // 4 waves (nodes) per block

  for (int L = 0; L < 3; ++L) {
    gemm2<<<dim3(gemmGridX, 2), 256, 0, stream>>>(hin, Wl[L], Wr[L], xl, xr, n);
    if (L < 2) {
      fused_attn<0><<<nodeBlocks, 256, 0, stream>>>(xl, xr, rowptr, csr, att[L],
                                                    bs[L], nullptr, nullptr, hbuf, n);
      hin = hbuf;
    } else {
      fused_attn<1><<<nodeBlocks, 256, 0, stream>>>(xl, xr, rowptr, csr, att[L],
                                                    bs[L], Wf, bf, (float*)d_out, n);
    }
  }
}

// Round 4
// 533.325 us; speedup vs baseline: 4.0123x; 1.2477x over previous
//
#include <hip/hip_runtime.h>

// GATv2 x3 + FC on MI355X. N=50000, E=800000(+N self loops), F=128, H=4, C=32.
// R3: (a) hierarchical 3-kernel CSR scan (was 110us single-block),
//     (b) fused_attn with 4 edges/wave (16 lanes/edge, 8 feats/lane),
//     (c) gemm2 BK=32 (half the barriers).
constexpr int FDIM = 128;   // H*C
constexpr float SLOPE = 0.2f;

__device__ __forceinline__ float lrelu(float x) {
  return x > 0.f ? x : x * SLOPE;
}

// ---------------- SGEMM: out = hin @ W for W in {Wl, Wr} -----------------
// BM=128, BN=128, BK=32, 256 threads, 8x8 per-thread register tile.
__global__ __launch_bounds__(256) void gemm2(
    const float* __restrict__ hin, const float* __restrict__ Wl,
    const float* __restrict__ Wr, float* __restrict__ xl,
    float* __restrict__ xr, int n) {
  const float* __restrict__ W = (blockIdx.y == 0) ? Wl : Wr;
  float* __restrict__ out = (blockIdx.y == 0) ? xl : xr;
  __shared__ __align__(16) float At[32][132];  // k-major A: At[k][row]
  __shared__ __align__(16) float Bs[32][132];
  const int tid = threadIdx.x;
  const int row0 = blockIdx.x * 128;
  const int tr = (tid >> 4) * 8;
  const int tc = (tid & 15) * 8;
  float acc[8][8];
#pragma unroll
  for (int i = 0; i < 8; ++i)
#pragma unroll
    for (int j = 0; j < 8; ++j) acc[i][j] = 0.f;

  for (int k0 = 0; k0 < 128; k0 += 32) {
    {  // stage A transposed: row r=tid>>1, 16 k-cols starting (tid&1)*16
      int r = tid >> 1, c0 = (tid & 1) * 16;
      int gr = row0 + r;
      float4 v[4];
#pragma unroll
      for (int u = 0; u < 4; ++u) v[u] = make_float4(0.f, 0.f, 0.f, 0.f);
      if (gr < n) {
#pragma unroll
        for (int u = 0; u < 4; ++u)
          v[u] = *(const float4*)(hin + (size_t)gr * FDIM + k0 + c0 + u * 4);
      }
#pragma unroll
      for (int u = 0; u < 4; ++u) {
        At[c0 + u * 4 + 0][r] = v[u].x;
        At[c0 + u * 4 + 1][r] = v[u].y;
        At[c0 + u * 4 + 2][r] = v[u].z;
        At[c0 + u * 4 + 3][r] = v[u].w;
      }
    }
    {  // stage B: row r=tid>>3 (0..31), 16 cols starting (tid&7)*16
      int r = tid >> 3, c0 = (tid & 7) * 16;
#pragma unroll
      for (int u = 0; u < 4; ++u) {
        float4 v = *(const float4*)(W + (size_t)(k0 + r) * FDIM + c0 + u * 4);
        *(float4*)&Bs[r][c0 + u * 4] = v;
      }
    }
    __syncthreads();
#pragma unroll
    for (int kk = 0; kk < 32; ++kk) {
      float4 a0 = *(const float4*)&At[kk][tr];
      float4 a1 = *(const float4*)&At[kk][tr + 4];
      float4 b0 = *(const float4*)&Bs[kk][tc];
      float4 b1 = *(const float4*)&Bs[kk][tc + 4];
      float av[8] = {a0.x, a0.y, a0.z, a0.w, a1.x, a1.y, a1.z, a1.w};
      float bv[8] = {b0.x, b0.y, b0.z, b0.w, b1.x, b1.y, b1.z, b1.w};
#pragma unroll
      for (int i = 0; i < 8; ++i)
#pragma unroll
        for (int j = 0; j < 8; ++j)
          acc[i][j] = fmaf(av[i], bv[j], acc[i][j]);
    }
    __syncthreads();
  }
#pragma unroll
  for (int i = 0; i < 8; ++i) {
    int gr = row0 + tr + i;
    if (gr < n) {
      float4 o0 = make_float4(acc[i][0], acc[i][1], acc[i][2], acc[i][3]);
      float4 o1 = make_float4(acc[i][4], acc[i][5], acc[i][6], acc[i][7]);
      *(float4*)(out + (size_t)gr * FDIM + tc) = o0;
      *(float4*)(out + (size_t)gr * FDIM + tc + 4) = o1;
    }
  }
}

// ---------------- CSR build: histogram -> hierarchical scan -> scatter ---
__global__ __launch_bounds__(256) void hist_dst(const int* __restrict__ dstI,
                                                int* __restrict__ deg, int e_cnt) {
  int i = blockIdx.x * blockDim.x + threadIdx.x;
  int stride = gridDim.x * blockDim.x;
  for (; i < e_cnt; i += stride) atomicAdd(&deg[dstI[i]], 1);
}

// local exclusive scan of deg per 1024-block; block totals out.
__global__ __launch_bounds__(1024) void scan_local(
    const int* __restrict__ deg, int* __restrict__ rowptr,
    int* __restrict__ btot, int n) {
  __shared__ int lds[1024];
  const int t = threadIdx.x;
  const int i = blockIdx.x * 1024 + t;
  int v = (i < n) ? deg[i] : 0;
  lds[t] = v;
  __syncthreads();
  for (int off = 1; off < 1024; off <<= 1) {
    int u = (t >= off) ? lds[t - off] : 0;
    __syncthreads();
    lds[t] += u;
    __syncthreads();
  }
  if (i < n) rowptr[i] = lds[t] - v;  // exclusive within block
  if (t == 1023) btot[blockIdx.x] = lds[1023];
}

// exclusive scan of block totals (nb <= 1024).
__global__ __launch_bounds__(1024) void scan_btot(int* __restrict__ btot, int nb) {
  __shared__ int lds[1024];
  const int t = threadIdx.x;
  int v = (t < nb) ? btot[t] : 0;
  lds[t] = v;
  __syncthreads();
  for (int off = 1; off < 1024; off <<= 1) {
    int u = (t >= off) ? lds[t - off] : 0;
    __syncthreads();
    lds[t] += u;
    __syncthreads();
  }
  if (t < nb) btot[t] = lds[t] - v;
}

// add block offsets; fill rowcur; set rowptr[n]=e_cnt.
__global__ __launch_bounds__(1024) void scan_add(
    int* __restrict__ rowptr, int* __restrict__ rowcur,
    const int* __restrict__ btot, int n, int e_cnt) {
  const int i = blockIdx.x * 1024 + threadIdx.x;
  if (i < n) {
    int v = rowptr[i] + btot[blockIdx.x];
    rowptr[i] = v;
    rowcur[i] = v;
  }
  if (i == 0) rowptr[n] = e_cnt;
}

__global__ __launch_bounds__(256) void scatter_csr(
    const int* __restrict__ srcI, const int* __restrict__ dstI,
    int* __restrict__ rowcur, int* __restrict__ csr, int e_cnt) {
  int i = blockIdx.x * blockDim.x + threadIdx.x;
  int stride = gridDim.x * blockDim.x;
  for (; i < e_cnt; i += stride) {
    int pos = atomicAdd(&rowcur[dstI[i]], 1);
    csr[pos] = srcI[i];
  }
}

// ------- fused per-node GATv2: 4 edges per wave, online softmax ----------
// lane = g*16 + q; group g handles edges rs+4t+g; lane q covers features
// q*8..q*8+7 (all one head, head = q>>2). Self-loop seeds group 0.
template <int LAST>
__global__ __launch_bounds__(256) void fused_attn(
    const float* __restrict__ xl, const float* __restrict__ xr,
    const int* __restrict__ rowptr, const int* __restrict__ csr,
    const float* __restrict__ att, const float* __restrict__ bias,
    const float* __restrict__ Wf, const float* __restrict__ bf,
    float* __restrict__ out, int n) {
  const int nid = (int)((blockIdx.x * (size_t)blockDim.x + threadIdx.x) >> 6);
  const int lane = threadIdx.x & 63;
  if (nid >= n) return;
  const int g = lane >> 4;
  const int q = lane & 15;
  const int f8 = q * 8;
  const float4 attA = *(const float4*)(att + f8);
  const float4 attB = *(const float4*)(att + f8 + 4);
  const float4 xrA = *(const float4*)(xr + (size_t)nid * FDIM + f8);
  const float4 xrB = *(const float4*)(xr + (size_t)nid * FDIM + f8 + 4);
  const float4 xldA = *(const float4*)(xl + (size_t)nid * FDIM + f8);
  const float4 xldB = *(const float4*)(xl + (size_t)nid * FDIM + f8 + 4);

  // self-edge logit (reduce over the 4-lane head quad)
  float ps = fmaf(lrelu(xldA.x + xrA.x), attA.x,
             fmaf(lrelu(xldA.y + xrA.y), attA.y,
             fmaf(lrelu(xldA.z + xrA.z), attA.z,
             fmaf(lrelu(xldA.w + xrA.w), attA.w,
             fmaf(lrelu(xldB.x + xrB.x), attB.x,
             fmaf(lrelu(xldB.y + xrB.y), attB.y,
             fmaf(lrelu(xldB.z + xrB.z), attB.z,
                  lrelu(xldB.w + xrB.w) * attB.w)))))));
  ps += __shfl_xor(ps, 1);
  ps += __shfl_xor(ps, 2);

  float m = (g == 0) ? ps : -1e30f;
  float s = (g == 0) ? 1.f : 0.f;
  float4 accA = (g == 0) ? xldA : make_float4(0.f, 0.f, 0.f, 0.f);
  float4 accB = (g == 0) ? xldB : make_float4(0.f, 0.f, 0.f, 0.f);

  const int rs = rowptr[nid], re = rowptr[nid + 1];
  int jj = rs + g;
  bool v = jj < re;
  int sidx = v ? csr[jj] : 0;
  float4 xaA = make_float4(0.f, 0.f, 0.f, 0.f), xaB = xaA;
  if (v) {
    xaA = *(const float4*)(xl + (size_t)sidx * FDIM + f8);
    xaB = *(const float4*)(xl + (size_t)sidx * FDIM + f8 + 4);
  }

  for (int t = rs; t < re; t += 4) {
    int jn = t + 4 + g;
    bool vn = jn < re;
    int sn = vn ? csr[jn] : 0;
    float4 xnA = make_float4(0.f, 0.f, 0.f, 0.f), xnB = xnA;
    if (vn) {
      xnA = *(const float4*)(xl + (size_t)sn * FDIM + f8);
      xnB = *(const float4*)(xl + (size_t)sn * FDIM + f8 + 4);
    }
    float p = fmaf(lrelu(xaA.x + xrA.x), attA.x,
              fmaf(lrelu(xaA.y + xrA.y), attA.y,
              fmaf(lrelu(xaA.z + xrA.z), attA.z,
              fmaf(lrelu(xaA.w + xrA.w), attA.w,
              fmaf(lrelu(xaB.x + xrB.x), attB.x,
              fmaf(lrelu(xaB.y + xrB.y), attB.y,
              fmaf(lrelu(xaB.z + xrB.z), attB.z,
                   lrelu(xaB.w + xrB.w) * attB.w)))))));
    p += __shfl_xor(p, 1);
    p += __shfl_xor(p, 2);
    if (v) {
      float mn = fmaxf(m, p);
      float sc = __expf(m - mn);
      float w = __expf(p - mn);
      s = fmaf(s, sc, w);
      accA.x = fmaf(accA.x, sc, w * xaA.x);
      accA.y = fmaf(accA.y, sc, w * xaA.y);
      accA.z = fmaf(accA.z, sc, w * xaA.z);
      accA.w = fmaf(accA.w, sc, w * xaA.w);
      accB.x = fmaf(accB.x, sc, w * xaB.x);
      accB.y = fmaf(accB.y, sc, w * xaB.y);
      accB.z = fmaf(accB.z, sc, w * xaB.z);
      accB.w = fmaf(accB.w, sc, w * xaB.w);
      m = mn;
    }
    v = vn; xaA = xnA; xaB = xnB;
  }

  // merge the 4 groups' online-softmax states (xor 16, then xor 32)
#pragma unroll
  for (int off = 16; off <= 32; off <<= 1) {
    float mo = __shfl_xor(m, off);
    float so = __shfl_xor(s, off);
    float4 aoA, aoB;
    aoA.x = __shfl_xor(accA.x, off); aoA.y = __shfl_xor(accA.y, off);
    aoA.z = __shfl_xor(accA.z, off); aoA.w = __shfl_xor(accA.w, off);
    aoB.x = __shfl_xor(accB.x, off); aoB.y = __shfl_xor(accB.y, off);
    aoB.z = __shfl_xor(accB.z, off); aoB.w = __shfl_xor(accB.w, off);
    float M = fmaxf(m, mo);
    float e0 = __expf(m - M), e1 = __expf(mo - M);
    s = fmaf(s, e0, so * e1);
    accA.x = fmaf(accA.x, e0, aoA.x * e1);
    accA.y = fmaf(accA.y, e0, aoA.y * e1);
    accA.z = fmaf(accA.z, e0, aoA.z * e1);
    accA.w = fmaf(accA.w, e0, aoA.w * e1);
    accB.x = fmaf(accB.x, e0, aoB.x * e1);
    accB.y = fmaf(accB.y, e0, aoB.y * e1);
    accB.z = fmaf(accB.z, e0, aoB.z * e1);
    accB.w = fmaf(accB.w, e0, aoB.w * e1);
    m = M;
  }

  const float inv = 1.f / s;
  const float4 bA = *(const float4*)(bias + f8);
  const float4 bB = *(const float4*)(bias + f8 + 4);
  float o0 = fmaxf(fmaf(accA.x, inv, bA.x), 0.f);
  float o1 = fmaxf(fmaf(accA.y, inv, bA.y), 0.f);
  float o2 = fmaxf(fmaf(accA.z, inv, bA.z), 0.f);
  float o3 = fmaxf(fmaf(accA.w, inv, bA.w), 0.f);
  float o4 = fmaxf(fmaf(accB.x, inv, bB.x), 0.f);
  float o5 = fmaxf(fmaf(accB.y, inv, bB.y), 0.f);
  float o6 = fmaxf(fmaf(accB.z, inv, bB.z), 0.f);
  float o7 = fmaxf(fmaf(accB.w, inv, bB.w), 0.f);

  if (LAST == 0) {
    if (g == 0) {
      *(float4*)(out + (size_t)nid * FDIM + f8) = make_float4(o0, o1, o2, o3);
      *(float4*)(out + (size_t)nid * FDIM + f8 + 4) = make_float4(o4, o5, o6, o7);
    }
  } else {
    const float4 wA = *(const float4*)(Wf + f8);
    const float4 wB = *(const float4*)(Wf + f8 + 4);
    float y = fmaf(o0, wA.x, fmaf(o1, wA.y, fmaf(o2, wA.z,
              fmaf(o3, wA.w, fmaf(o4, wB.x, fmaf(o5, wB.y,
              fmaf(o6, wB.z, o7 * wB.w)))))));
    y += __shfl_xor(y, 1);
    y += __shfl_xor(y, 2);
    y += __shfl_xor(y, 4);
    y += __shfl_xor(y, 8);
    if (lane == 0) out[nid] = y + bf[0];
  }
}

extern "C" void kernel_launch(void* const* d_in, const int* in_sizes, int n_in,
                              void* d_out, int out_size, void* d_ws, size_t ws_size,
                              hipStream_t stream) {
  const float* x = (const float*)d_in[0];
  const int* ei = (const int*)d_in[1];
  const int n = in_sizes[0] / FDIM;
  const int e_cnt = in_sizes[1] / 2;
  const int* srcI = ei;
  const int* dstI = ei + e_cnt;

  const float* Wl[3]  = {(const float*)d_in[2], (const float*)d_in[6], (const float*)d_in[10]};
  const float* Wr[3]  = {(const float*)d_in[3], (const float*)d_in[7], (const float*)d_in[11]};
  const float* att[3] = {(const float*)d_in[4], (const float*)d_in[8], (const float*)d_in[12]};
  const float* bs[3]  = {(const float*)d_in[5], (const float*)d_in[9], (const float*)d_in[13]};
  const float* Wf = (const float*)d_in[14];
  const float* bf = (const float*)d_in[15];

  float* ws = (float*)d_ws;
  float* xl   = ws;
  float* xr   = xl + (size_t)n * FDIM;
  float* hbuf = xr + (size_t)n * FDIM;
  int* deg    = (int*)(hbuf + (size_t)n * FDIM);
  int* rowptr = deg + n;
  int* rowcur = rowptr + n + 1;
  int* csr    = rowcur + n;
  int* btot   = csr + e_cnt;

  const int nb = (n + 1023) / 1024;

  // ---- CSR build (once per call; serves all 3 layers) ----
  hipMemsetAsync(deg, 0, (size_t)n * sizeof(int), stream);
  hist_dst<<<(e_cnt + 255) / 256, 256, 0, stream>>>(dstI, deg, e_cnt);
  scan_local<<<nb, 1024, 0, stream>>>(deg, rowptr, btot, n);
  scan_btot<<<1, 1024, 0, stream>>>(btot, nb);
  scan_add<<<nb, 1024, 0, stream>>>(rowptr, rowcur, btot, n, e_cnt);
  scatter_csr<<<(e_cnt + 255) / 256, 256, 0, stream>>>(srcI, dstI, rowcur, csr, e_cnt);

  const float* hin = x;
  const int gemmGridX = (n + 127) / 128;
  const int nodeBlocks = (n + 3) / 4;  // 4 waves (nodes) per block

  for (int L = 0; L < 3; ++L) {
    gemm2<<<dim3(gemmGridX, 2), 256, 0, stream>>>(hin, Wl[L], Wr[L], xl, xr, n);
    if (L < 2) {
      fused_attn<0><<<nodeBlocks, 256, 0, stream>>>(xl, xr, rowptr, csr, att[L],
                                                    bs[L], nullptr, nullptr, hbuf, n);
      hin = hbuf;
    } else {
      fused_attn<1><<<nodeBlocks, 256, 0, stream>>>(xl, xr, rowptr, csr, att[L],
                                                    bs[L], Wf, bf, (float*)d_out, n);
    }
  }
}

// Round 5
// 489.215 us; speedup vs baseline: 4.3741x; 1.0902x over previous
//
#include <hip/hip_runtime.h>
#include <hip/hip_fp16.h>

// GATv2 x3 + FC on MI355X. N=50000, E=800000(+N self loops), F=128, H=4, C=32.
// R4: xl/xr stored as fp16 -> per-edge gather 512B->256B (attn was 43% HBM /
//     199MB L2-miss per dispatch). GEMM math stays fp32; only epilogue casts.
constexpr int FDIM = 128;   // H*C
constexpr float SLOPE = 0.2f;

__device__ __forceinline__ float lrelu(float x) {
  return x > 0.f ? x : x * SLOPE;
}

struct F8 { float4 a, b; };
__device__ __forceinline__ F8 cvt8(uint4 u) {
  union { uint4 u; __half2 h[4]; } t;
  t.u = u;
  float2 f0 = __half22float2(t.h[0]);
  float2 f1 = __half22float2(t.h[1]);
  float2 f2 = __half22float2(t.h[2]);
  float2 f3 = __half22float2(t.h[3]);
  F8 r;
  r.a = make_float4(f0.x, f0.y, f1.x, f1.y);
  r.b = make_float4(f2.x, f2.y, f3.x, f3.y);
  return r;
}

// ---------------- SGEMM: out = hin @ W for W in {Wl, Wr}, fp16 out -------
// BM=128, BN=128, BK=32, 256 threads, 8x8 per-thread register tile.
__global__ __launch_bounds__(256) void gemm2(
    const float* __restrict__ hin, const float* __restrict__ Wl,
    const float* __restrict__ Wr, __half* __restrict__ xl,
    __half* __restrict__ xr, int n) {
  const float* __restrict__ W = (blockIdx.y == 0) ? Wl : Wr;
  __half* __restrict__ out = (blockIdx.y == 0) ? xl : xr;
  __shared__ __align__(16) float At[32][132];  // k-major A: At[k][row]
  __shared__ __align__(16) float Bs[32][132];
  const int tid = threadIdx.x;
  const int row0 = blockIdx.x * 128;
  const int tr = (tid >> 4) * 8;
  const int tc = (tid & 15) * 8;
  float acc[8][8];
#pragma unroll
  for (int i = 0; i < 8; ++i)
#pragma unroll
    for (int j = 0; j < 8; ++j) acc[i][j] = 0.f;

  for (int k0 = 0; k0 < 128; k0 += 32) {
    {  // stage A transposed: row r=tid>>1, 16 k-cols starting (tid&1)*16
      int r = tid >> 1, c0 = (tid & 1) * 16;
      int gr = row0 + r;
      float4 v[4];
#pragma unroll
      for (int u = 0; u < 4; ++u) v[u] = make_float4(0.f, 0.f, 0.f, 0.f);
      if (gr < n) {
#pragma unroll
        for (int u = 0; u < 4; ++u)
          v[u] = *(const float4*)(hin + (size_t)gr * FDIM + k0 + c0 + u * 4);
      }
#pragma unroll
      for (int u = 0; u < 4; ++u) {
        At[c0 + u * 4 + 0][r] = v[u].x;
        At[c0 + u * 4 + 1][r] = v[u].y;
        At[c0 + u * 4 + 2][r] = v[u].z;
        At[c0 + u * 4 + 3][r] = v[u].w;
      }
    }
    {  // stage B: row r=tid>>3 (0..31), 16 cols starting (tid&7)*16
      int r = tid >> 3, c0 = (tid & 7) * 16;
#pragma unroll
      for (int u = 0; u < 4; ++u) {
        float4 v = *(const float4*)(W + (size_t)(k0 + r) * FDIM + c0 + u * 4);
        *(float4*)&Bs[r][c0 + u * 4] = v;
      }
    }
    __syncthreads();
#pragma unroll
    for (int kk = 0; kk < 32; ++kk) {
      float4 a0 = *(const float4*)&At[kk][tr];
      float4 a1 = *(const float4*)&At[kk][tr + 4];
      float4 b0 = *(const float4*)&Bs[kk][tc];
      float4 b1 = *(const float4*)&Bs[kk][tc + 4];
      float av[8] = {a0.x, a0.y, a0.z, a0.w, a1.x, a1.y, a1.z, a1.w};
      float bv[8] = {b0.x, b0.y, b0.z, b0.w, b1.x, b1.y, b1.z, b1.w};
#pragma unroll
      for (int i = 0; i < 8; ++i)
#pragma unroll
        for (int j = 0; j < 8; ++j)
          acc[i][j] = fmaf(av[i], bv[j], acc[i][j]);
    }
    __syncthreads();
  }
#pragma unroll
  for (int i = 0; i < 8; ++i) {
    int gr = row0 + tr + i;
    if (gr < n) {
      union { uint4 u; __half2 h[4]; } pk;
      pk.h[0] = __floats2half2_rn(acc[i][0], acc[i][1]);
      pk.h[1] = __floats2half2_rn(acc[i][2], acc[i][3]);
      pk.h[2] = __floats2half2_rn(acc[i][4], acc[i][5]);
      pk.h[3] = __floats2half2_rn(acc[i][6], acc[i][7]);
      *(uint4*)(out + (size_t)gr * FDIM + tc) = pk.u;
    }
  }
}

// ---------------- CSR build: histogram -> hierarchical scan -> scatter ---
__global__ __launch_bounds__(256) void hist_dst(const int* __restrict__ dstI,
                                                int* __restrict__ deg, int e_cnt) {
  int i = blockIdx.x * blockDim.x + threadIdx.x;
  int stride = gridDim.x * blockDim.x;
  for (; i < e_cnt; i += stride) atomicAdd(&deg[dstI[i]], 1);
}

__global__ __launch_bounds__(1024) void scan_local(
    const int* __restrict__ deg, int* __restrict__ rowptr,
    int* __restrict__ btot, int n) {
  __shared__ int lds[1024];
  const int t = threadIdx.x;
  const int i = blockIdx.x * 1024 + t;
  int v = (i < n) ? deg[i] : 0;
  lds[t] = v;
  __syncthreads();
  for (int off = 1; off < 1024; off <<= 1) {
    int u = (t >= off) ? lds[t - off] : 0;
    __syncthreads();
    lds[t] += u;
    __syncthreads();
  }
  if (i < n) rowptr[i] = lds[t] - v;  // exclusive within block
  if (t == 1023) btot[blockIdx.x] = lds[1023];
}

__global__ __launch_bounds__(1024) void scan_btot(int* __restrict__ btot, int nb) {
  __shared__ int lds[1024];
  const int t = threadIdx.x;
  int v = (t < nb) ? btot[t] : 0;
  lds[t] = v;
  __syncthreads();
  for (int off = 1; off < 1024; off <<= 1) {
    int u = (t >= off) ? lds[t - off] : 0;
    __syncthreads();
    lds[t] += u;
    __syncthreads();
  }
  if (t < nb) btot[t] = lds[t] - v;
}

__global__ __launch_bounds__(1024) void scan_add(
    int* __restrict__ rowptr, int* __restrict__ rowcur,
    const int* __restrict__ btot, int n, int e_cnt) {
  const int i = blockIdx.x * 1024 + threadIdx.x;
  if (i < n) {
    int v = rowptr[i] + btot[blockIdx.x];
    rowptr[i] = v;
    rowcur[i] = v;
  }
  if (i == 0) rowptr[n] = e_cnt;
}

__global__ __launch_bounds__(256) void scatter_csr(
    const int* __restrict__ srcI, const int* __restrict__ dstI,
    int* __restrict__ rowcur, int* __restrict__ csr, int e_cnt) {
  int i = blockIdx.x * blockDim.x + threadIdx.x;
  int stride = gridDim.x * blockDim.x;
  for (; i < e_cnt; i += stride) {
    int pos = atomicAdd(&rowcur[dstI[i]], 1);
    csr[pos] = srcI[i];
  }
}

// ------- fused per-node GATv2: 4 edges per wave, fp16 gathers ------------
// lane = g*16 + q; group g handles edges rs+4t+g; lane q covers features
// q*8..q*8+7 (head = q>>2). Self-loop seeds group 0's state.
template <int LAST>
__global__ __launch_bounds__(256) void fused_attn(
    const __half* __restrict__ xl, const __half* __restrict__ xr,
    const int* __restrict__ rowptr, const int* __restrict__ csr,
    const float* __restrict__ att, const float* __restrict__ bias,
    const float* __restrict__ Wf, const float* __restrict__ bf,
    float* __restrict__ out, int n) {
  const int nid = (int)((blockIdx.x * (size_t)blockDim.x + threadIdx.x) >> 6);
  const int lane = threadIdx.x & 63;
  if (nid >= n) return;
  const int g = lane >> 4;
  const int q = lane & 15;
  const int f8 = q * 8;
  const float4 attA = *(const float4*)(att + f8);
  const float4 attB = *(const float4*)(att + f8 + 4);
  const F8 xrv = cvt8(*(const uint4*)(xr + (size_t)nid * FDIM + f8));
  const F8 xld = cvt8(*(const uint4*)(xl + (size_t)nid * FDIM + f8));
  const float4 xrA = xrv.a, xrB = xrv.b;
  const float4 xldA = xld.a, xldB = xld.b;

  // self-edge logit (reduce over the 4-lane head quad)
  float ps = fmaf(lrelu(xldA.x + xrA.x), attA.x,
             fmaf(lrelu(xldA.y + xrA.y), attA.y,
             fmaf(lrelu(xldA.z + xrA.z), attA.z,
             fmaf(lrelu(xldA.w + xrA.w), attA.w,
             fmaf(lrelu(xldB.x + xrB.x), attB.x,
             fmaf(lrelu(xldB.y + xrB.y), attB.y,
             fmaf(lrelu(xldB.z + xrB.z), attB.z,
                  lrelu(xldB.w + xrB.w) * attB.w)))))));
  ps += __shfl_xor(ps, 1);
  ps += __shfl_xor(ps, 2);

  float m = (g == 0) ? ps : -1e30f;
  float s = (g == 0) ? 1.f : 0.f;
  float4 accA = (g == 0) ? xldA : make_float4(0.f, 0.f, 0.f, 0.f);
  float4 accB = (g == 0) ? xldB : make_float4(0.f, 0.f, 0.f, 0.f);

  const int rs = rowptr[nid], re = rowptr[nid + 1];
  int jj = rs + g;
  bool v = jj < re;
  int sidx = v ? csr[jj] : 0;
  uint4 cur = make_uint4(0u, 0u, 0u, 0u);
  if (v) cur = *(const uint4*)(xl + (size_t)sidx * FDIM + f8);

  for (int t = rs; t < re; t += 4) {
    int jn = t + 4 + g;
    bool vn = jn < re;
    int sn = vn ? csr[jn] : 0;
    uint4 nxt = make_uint4(0u, 0u, 0u, 0u);
    if (vn) nxt = *(const uint4*)(xl + (size_t)sn * FDIM + f8);
    F8 xa = cvt8(cur);
    float4 xaA = xa.a, xaB = xa.b;
    float p = fmaf(lrelu(xaA.x + xrA.x), attA.x,
              fmaf(lrelu(xaA.y + xrA.y), attA.y,
              fmaf(lrelu(xaA.z + xrA.z), attA.z,
              fmaf(lrelu(xaA.w + xrA.w), attA.w,
              fmaf(lrelu(xaB.x + xrB.x), attB.x,
              fmaf(lrelu(xaB.y + xrB.y), attB.y,
              fmaf(lrelu(xaB.z + xrB.z), attB.z,
                   lrelu(xaB.w + xrB.w) * attB.w)))))));
    p += __shfl_xor(p, 1);
    p += __shfl_xor(p, 2);
    if (v) {
      float mn = fmaxf(m, p);
      float sc = __expf(m - mn);
      float w = __expf(p - mn);
      s = fmaf(s, sc, w);
      accA.x = fmaf(accA.x, sc, w * xaA.x);
      accA.y = fmaf(accA.y, sc, w * xaA.y);
      accA.z = fmaf(accA.z, sc, w * xaA.z);
      accA.w = fmaf(accA.w, sc, w * xaA.w);
      accB.x = fmaf(accB.x, sc, w * xaB.x);
      accB.y = fmaf(accB.y, sc, w * xaB.y);
      accB.z = fmaf(accB.z, sc, w * xaB.z);
      accB.w = fmaf(accB.w, sc, w * xaB.w);
      m = mn;
    }
    v = vn; cur = nxt;
  }

  // merge the 4 groups' online-softmax states (xor 16, then xor 32)
#pragma unroll
  for (int off = 16; off <= 32; off <<= 1) {
    float mo = __shfl_xor(m, off);
    float so = __shfl_xor(s, off);
    float4 aoA, aoB;
    aoA.x = __shfl_xor(accA.x, off); aoA.y = __shfl_xor(accA.y, off);
    aoA.z = __shfl_xor(accA.z, off); aoA.w = __shfl_xor(accA.w, off);
    aoB.x = __shfl_xor(accB.x, off); aoB.y = __shfl_xor(accB.y, off);
    aoB.z = __shfl_xor(accB.z, off); aoB.w = __shfl_xor(accB.w, off);
    float M = fmaxf(m, mo);
    float e0 = __expf(m - M), e1 = __expf(mo - M);
    s = fmaf(s, e0, so * e1);
    accA.x = fmaf(accA.x, e0, aoA.x * e1);
    accA.y = fmaf(accA.y, e0, aoA.y * e1);
    accA.z = fmaf(accA.z, e0, aoA.z * e1);
    accA.w = fmaf(accA.w, e0, aoA.w * e1);
    accB.x = fmaf(accB.x, e0, aoB.x * e1);
    accB.y = fmaf(accB.y, e0, aoB.y * e1);
    accB.z = fmaf(accB.z, e0, aoB.z * e1);
    accB.w = fmaf(accB.w, e0, aoB.w * e1);
    m = M;
  }

  const float inv = 1.f / s;
  const float4 bA = *(const float4*)(bias + f8);
  const float4 bB = *(const float4*)(bias + f8 + 4);
  float o0 = fmaxf(fmaf(accA.x, inv, bA.x), 0.f);
  float o1 = fmaxf(fmaf(accA.y, inv, bA.y), 0.f);
  float o2 = fmaxf(fmaf(accA.z, inv, bA.z), 0.f);
  float o3 = fmaxf(fmaf(accA.w, inv, bA.w), 0.f);
  float o4 = fmaxf(fmaf(accB.x, inv, bB.x), 0.f);
  float o5 = fmaxf(fmaf(accB.y, inv, bB.y), 0.f);
  float o6 = fmaxf(fmaf(accB.z, inv, bB.z), 0.f);
  float o7 = fmaxf(fmaf(accB.w, inv, bB.w), 0.f);

  if (LAST == 0) {
    if (g == 0) {
      *(float4*)(out + (size_t)nid * FDIM + f8) = make_float4(o0, o1, o2, o3);
      *(float4*)(out + (size_t)nid * FDIM + f8 + 4) = make_float4(o4, o5, o6, o7);
    }
  } else {
    const float4 wA = *(const float4*)(Wf + f8);
    const float4 wB = *(const float4*)(Wf + f8 + 4);
    float y = fmaf(o0, wA.x, fmaf(o1, wA.y, fmaf(o2, wA.z,
              fmaf(o3, wA.w, fmaf(o4, wB.x, fmaf(o5, wB.y,
              fmaf(o6, wB.z, o7 * wB.w)))))));
    y += __shfl_xor(y, 1);
    y += __shfl_xor(y, 2);
    y += __shfl_xor(y, 4);
    y += __shfl_xor(y, 8);
    if (lane == 0) out[nid] = y + bf[0];
  }
}

extern "C" void kernel_launch(void* const* d_in, const int* in_sizes, int n_in,
                              void* d_out, int out_size, void* d_ws, size_t ws_size,
                              hipStream_t stream) {
  const float* x = (const float*)d_in[0];
  const int* ei = (const int*)d_in[1];
  const int n = in_sizes[0] / FDIM;
  const int e_cnt = in_sizes[1] / 2;
  const int* srcI = ei;
  const int* dstI = ei + e_cnt;

  const float* Wl[3]  = {(const float*)d_in[2], (const float*)d_in[6], (const float*)d_in[10]};
  const float* Wr[3]  = {(const float*)d_in[3], (const float*)d_in[7], (const float*)d_in[11]};
  const float* att[3] = {(const float*)d_in[4], (const float*)d_in[8], (const float*)d_in[12]};
  const float* bs[3]  = {(const float*)d_in[5], (const float*)d_in[9], (const float*)d_in[13]};
  const float* Wf = (const float*)d_in[14];
  const float* bf = (const float*)d_in[15];

  __half* xlh = (__half*)d_ws;
  __half* xrh = xlh + (size_t)n * FDIM;
  float* hbuf = (float*)(xrh + (size_t)n * FDIM);
  int* deg    = (int*)(hbuf + (size_t)n * FDIM);
  int* rowptr = deg + n;
  int* rowcur = rowptr + n + 1;
  int* csr    = rowcur + n;
  int* btot   = csr + e_cnt;

  const int nb = (n + 1023) / 1024;

  // ---- CSR build (once per call; serves all 3 layers) ----
  hipMemsetAsync(deg, 0, (size_t)n * sizeof(int), stream);
  hist_dst<<<(e_cnt + 255) / 256, 256, 0, stream>>>(dstI, deg, e_cnt);
  scan_local<<<nb, 1024, 0, stream>>>(deg, rowptr, btot, n);
  scan_btot<<<1, 1024, 0, stream>>>(btot, nb);
  scan_add<<<nb, 1024, 0, stream>>>(rowptr, rowcur, btot, n, e_cnt);
  scatter_csr<<<(e_cnt + 255) / 256, 256, 0, stream>>>(srcI, dstI, rowcur, csr, e_cnt);

  const float* hin = x;
  const int gemmGridX = (n + 127) / 128;
  const int nodeBlocks = (n + 3) / 4;  // 4 waves (nodes) per block

  for (int L = 0; L < 3; ++L) {
    gemm2<<<dim3(gemmGridX, 2), 256, 0, stream>>>(hin, Wl[L], Wr[L], xlh, xrh, n);
    if (L < 2) {
      fused_attn<0><<<nodeBlocks, 256, 0, stream>>>(xlh, xrh, rowptr, csr, att[L],
                                                    bs[L], nullptr, nullptr, hbuf, n);
      hin = hbuf;
    } else {
      fused_attn<1><<<nodeBlocks, 256, 0, stream>>>(xlh, xrh, rowptr, csr, att[L],
                                                    bs[L], Wf, bf, (float*)d_out, n);
    }
  }
}